// Round 17
// baseline (49.927 us; speedup 1.0000x reference)
//
#include <hip/hip_runtime.h>
#include <hip/hip_bf16.h>
#include <math.h>

#define NBATCH 8
#define NL 128
#define IND 512
#define DEPN 45
#define DEPD 16
#define WCOLS 528          // IN_DIM + DEP_DIM
#define NP 1664            // Pout row stride (only D region written now)
#define C_P1 0
#define C_P2 512
#define C_HT 1024
#define C_D1 1536
#define C_D2 1581
#define C_PAD 1626

typedef __attribute__((ext_vector_type(8))) short bf16x8;
typedef __attribute__((ext_vector_type(4))) float f32x4;

__device__ inline ushort f2bf(float x) {
    __hip_bfloat16 b = __float2bfloat16(x);
    return *reinterpret_cast<ushort*>(&b);
}
__device__ inline float bf2f(ushort u) {
    __hip_bfloat16 b;
    *reinterpret_cast<ushort*>(&b) = u;
    return __bfloat162float(b);
}

__device__ __forceinline__ void gl16(const ushort* g, ushort* l) {
    __builtin_amdgcn_global_load_lds(
        (const __attribute__((address_space(1))) unsigned int*)g,
        (__attribute__((address_space(3))) unsigned int*)l, 16, 0, 0);
}

// ================= k_prep (R16 + c0buf zeroing) =================
__global__ __launch_bounds__(256) void k_prep(
    const float* __restrict__ h, const unsigned char* __restrict__ mask,
    const float* __restrict__ emb,
    const float* __restrict__ W1, const float* __restrict__ W2,
    const float* __restrict__ Wg,
    const float* __restrict__ b1, const float* __restrict__ b2,
    const float* __restrict__ bg,
    ushort* __restrict__ A_hi, ushort* __restrict__ A_lo,
    ushort* __restrict__ B_hi, ushort* __restrict__ B_lo,
    float* __restrict__ bias_ext, float* __restrict__ c0buf) {
    int bid = blockIdx.x;
    int tid = threadIdx.x;

    if (bid < 64) {
        int rb = bid * 16;
        int b = rb >> 7;
        __shared__ int sflag, smin, smax;
        __shared__ float w16[16];
        if (tid == 0) { sflag = 0; smin = NL; smax = -1; }
        __syncthreads();
        const int* mi = (const int*)mask;
        if (tid < 128) {
            int v0 = mi[tid], v1 = mi[tid + 128];
            if ((unsigned)v0 > 1u || (unsigned)v1 > 1u) atomicOr(&sflag, 1);
        }
        __syncthreads();
        if (tid < 128) {
            int mval = sflag ? (int)mask[b * NL + tid] : mi[b * NL + tid];
            if (mval) { atomicMin(&smin, tid); atomicMax(&smax, tid); }
        }
        __syncthreads();
        if (tid < 16) {
            int any = (smax >= 0);
            int s = any ? smin : 0;
            int e = any ? smax : (NL - 1);
            int i = (rb & 127) + tid;
            const float invL = 1.0f / (float)NL;
            float w;
            if (i < s)      w = 1.0f - (float)(s - i) * invL;
            else if (i > e) w = 1.0f - (float)(i - e) * invL;
            else            w = 0.0f;
            int mval = sflag ? (int)mask[b * NL + i] : mi[b * NL + i];
            if (mval) w = 0.0f;
            w16[tid] = w;
        }
        __syncthreads();
        for (int idx = tid; idx < 16 * 128; idx += 256) {
            int r = idx >> 7, dc = (idx & 127) << 2;
            float4 hv = *(const float4*)&h[(size_t)(rb + r) * IND + dc];
            float wv = w16[r];
            hv.x *= wv; hv.y *= wv; hv.z *= wv; hv.w *= wv;
            ushort4 hi4, lo4;
            hi4.x = f2bf(hv.x); hi4.y = f2bf(hv.y); hi4.z = f2bf(hv.z); hi4.w = f2bf(hv.w);
            lo4.x = f2bf(hv.x - bf2f(hi4.x));
            lo4.y = f2bf(hv.y - bf2f(hi4.y));
            lo4.z = f2bf(hv.z - bf2f(hi4.z));
            lo4.w = f2bf(hv.w - bf2f(hi4.w));
            *(ushort4*)&A_hi[(size_t)(rb + r) * IND + dc] = hi4;
            *(ushort4*)&A_lo[(size_t)(rb + r) * IND + dc] = lo4;
        }
        if (bid == 0) {
            for (int i = tid; i < 512; i += 256) {
                bias_ext[C_P1 + i] = b1[i];
                bias_ext[C_P2 + i] = b2[i];
                bias_ext[C_HT + i] = bg[i];
            }
            if (tid < NP - C_PAD) bias_ext[C_PAD + tid] = 0.f;
            for (int i = tid; i < 1024; i += 256) c0buf[i] = 0.f;
        }
    } else if (bid < 160) {
        int nb = (bid - 64) * 16;
        for (int idx = tid; idx < 16 * 128; idx += 256) {
            int r = idx >> 7, dc = (idx & 127) << 2;
            int n = nb + r;
            const float* src;
            if (n < 512)       src = W1 + (size_t)n * WCOLS + dc;
            else if (n < 1024) src = W2 + (size_t)(n - 512) * WCOLS + dc;
            else               src = Wg + (size_t)(n - 1024) * IND + dc;
            float4 wv = *(const float4*)src;
            ushort4 hi4;
            hi4.x = f2bf(wv.x); hi4.y = f2bf(wv.y); hi4.z = f2bf(wv.z); hi4.w = f2bf(wv.w);
            *(ushort4*)&B_hi[(size_t)n * IND + dc] = hi4;
            if (n >= 1024) {
                ushort4 lo4;
                lo4.x = f2bf(wv.x - bf2f(hi4.x));
                lo4.y = f2bf(wv.y - bf2f(hi4.y));
                lo4.z = f2bf(wv.z - bf2f(hi4.z));
                lo4.w = f2bf(wv.w - bf2f(hi4.w));
                *(ushort4*)&B_lo[(size_t)n * IND + dc] = lo4;
            }
        }
    } else if (bid < 162) {
        int nb = 1626 + (bid - 160) * 19;
        ushort4 z4 = {0, 0, 0, 0};
        for (int idx = tid; idx < 19 * 128; idx += 256) {
            int r = idx >> 7, dc = (idx & 127) << 2;
            *(ushort4*)&B_hi[(size_t)(nb + r) * IND + dc] = z4;
            *(ushort4*)&B_lo[(size_t)(nb + r) * IND + dc] = z4;
        }
    } else if (bid < 234) {
        int zi = bid - 162;               // 0..71
        int m = zi / 36;
        int rest = zi % 36;
        int dq = rest / 9;
        int tq = rest % 9;
        int tb = tq * 5;
        __shared__ float es5[5][DEPD];
        __shared__ float ys5[5][512];
        __shared__ float part[5][256];
        if (tid < 5 * DEPD) es5[tid >> 4][tid & 15] = emb[(tb + (tid >> 4)) * DEPD + (tid & 15)];
        __syncthreads();
        const float* Wdep = (m == 0) ? W2 : W1;
        for (int idx = tid; idx < 5 * 512; idx += 256) {
            int tt = idx >> 9, o = idx & 511;
            float s = 0.f;
#pragma unroll
            for (int e = 0; e < DEPD; e++) s += es5[tt][e] * Wdep[o * WCOLS + IND + e];
            ys5[tt][o] = s;
        }
        __syncthreads();
        int dloc = tid & 127, half = tid >> 7;
        const float* Wsrc = (m == 0) ? W1 : W2;
        int d = dq * 128 + dloc;
        int obase = half * 256;
        float ac0 = 0.f, ac1 = 0.f, ac2 = 0.f, ac3 = 0.f, ac4 = 0.f;
#pragma unroll 8
        for (int oo = 0; oo < 256; oo++) {
            float w = Wsrc[(size_t)(obase + oo) * WCOLS + d];
            int o = obase + oo;
            ac0 += w * ys5[0][o];
            ac1 += w * ys5[1][o];
            ac2 += w * ys5[2][o];
            ac3 += w * ys5[3][o];
            ac4 += w * ys5[4][o];
        }
        part[0][tid] = ac0; part[1][tid] = ac1; part[2][tid] = ac2;
        part[3][tid] = ac3; part[4][tid] = ac4;
        __syncthreads();
        if (half == 0) {
#pragma unroll
            for (int tt = 0; tt < 5; tt++) {
                float tot = part[tt][dloc] + part[tt][128 + dloc];
                int row = ((m == 0) ? C_D1 : C_D2) + tb + tt;
                ushort hi = f2bf(tot);
                B_hi[(size_t)row * IND + d] = hi;
                B_lo[(size_t)row * IND + d] = f2bf(tot - bf2f(hi));
            }
        }
    } else {
        int zi2 = bid - 234;              // 0..89
        int t = zi2 % 45;
        int m = zi2 / 45;
        __shared__ float es[DEPD];
        __shared__ float ys[512];
        __shared__ float y1s[512];
        if (tid < DEPD) es[tid] = emb[t * DEPD + tid];
        __syncthreads();
        const float* Wdep = (m == 0) ? W2 : W1;
        for (int o = tid; o < 512; o += 256) {
            float s = 0.f;
#pragma unroll
            for (int e = 0; e < DEPD; e++) s += es[e] * Wdep[o * WCOLS + IND + e];
            ys[o] = s;
        }
        if (m == 0) {
            for (int o = tid; o < 512; o += 256) {
                float s = 0.f;
#pragma unroll
                for (int e = 0; e < DEPD; e++) s += es[e] * W1[o * WCOLS + IND + e];
                y1s[o] = s;
            }
        }
        __syncthreads();
        if (tid < 64) {
            const float* bb = (m == 0) ? b1 : b2;
            float sb = 0.f;
#pragma unroll
            for (int k = 0; k < 8; k++) sb += bb[tid + k * 64] * ys[tid + k * 64];
            if (m == 0) {
#pragma unroll
                for (int k = 0; k < 8; k++) sb += y1s[tid + k * 64] * ys[tid + k * 64];
            }
            for (int off = 32; off; off >>= 1) sb += __shfl_down(sb, off, 64);
            if (tid == 0) bias_ext[((m == 0) ? C_D1 : C_D2) + t] = sb;
        }
    }
}

// ================= k3: tiered GEMM; paired P1/P2 chunks reduce to c0 =================
// Grid (16, 18), 256 thr = 4 waves. y<8: paired chunk j=y computes P1 cols
// [64j,64j+64) AND P2 cols [512+64j,...), multiplies elementwise, reduces
// over the 16-lane col group, atomicAdds per-row partials into c0buf.
// y>=8: heavy 3-term chunk over cols 1024 + (y-8)*64 (HT -> HTb bf16,
// D1/D2/pad -> Pout fp32). Double-buffered LDS, global_load_lds staging.
__global__ __launch_bounds__(256) void k3_gemm(
    const ushort* __restrict__ A_hi, const ushort* __restrict__ A_lo,
    const ushort* __restrict__ B_hi, const ushort* __restrict__ B_lo,
    const float* __restrict__ bias_ext, float* __restrict__ Pout,
    ushort* __restrict__ HTb, float* __restrict__ c0buf) {
    int tid = threadIdx.x;
    int wid = tid >> 6, lane = tid & 63;
    int lrow = lane & 15;
    int mbase = blockIdx.x * 64;
    int y = blockIdx.y;
    int mh = (wid >> 1) << 5;
    int nh = (wid & 1) << 5;
    int r0 = (lane >> 4) << 2;
    int rowb = mbase + mh;

    __shared__ ushort Ah[2][8 * 64 * 8];
    __shared__ ushort Al[2][8 * 64 * 8];   // paired path: B2h lives here
    __shared__ ushort Bh[2][8 * 64 * 8];
    __shared__ ushort Bl[2][8 * 64 * 8];

    if (y >= 8) {
        // ---------- heavy 3-term chunk (HT | D1 | D2 | pad) ----------
        int nbase = 1024 + ((y - 8) << 6);
        const ushort* aH = A_hi + (size_t)(mbase + lane) * IND;
        const ushort* aL = A_lo + (size_t)(mbase + lane) * IND;
        const ushort* bH = B_hi + (size_t)(nbase + lane) * IND;
        const ushort* bL = B_lo + (size_t)(nbase + lane) * IND;
        f32x4 acc00 = {0.f, 0.f, 0.f, 0.f};
        f32x4 acc01 = acc00, acc10 = acc00, acc11 = acc00;
#define STAGE(BUF, C) { \
    int ck = (C) << 6; \
    if (wid == 0) { \
        _Pragma("unroll") \
        for (int g = 0; g < 8; g++) gl16(aH + ck + (g << 3), &Ah[BUF][g << 9]); \
    } else if (wid == 1) { \
        _Pragma("unroll") \
        for (int g = 0; g < 8; g++) gl16(aL + ck + (g << 3), &Al[BUF][g << 9]); \
    } else if (wid == 2) { \
        _Pragma("unroll") \
        for (int g = 0; g < 8; g++) gl16(bH + ck + (g << 3), &Bh[BUF][g << 9]); \
    } else { \
        _Pragma("unroll") \
        for (int g = 0; g < 8; g++) gl16(bL + ck + (g << 3), &Bl[BUF][g << 9]); \
    } }
        STAGE(0, 0)
        for (int c = 0; c < 8; c++) {
            int cb = c & 1;
            __syncthreads();
            if (c < 7) STAGE(cb ^ 1, c + 1)
#pragma unroll
            for (int KS = 0; KS < 2; KS++) {
                int gA = (KS << 2) + (lane >> 4);
                int ga = ((gA << 6) + mh + lrow) << 3;
                int gb = ((gA << 6) + nh + lrow) << 3;
                bf16x8 a0h = *(const bf16x8*)&Ah[cb][ga];
                bf16x8 a0l = *(const bf16x8*)&Al[cb][ga];
                bf16x8 a1h = *(const bf16x8*)&Ah[cb][ga + 128];
                bf16x8 a1l = *(const bf16x8*)&Al[cb][ga + 128];
                bf16x8 b0h = *(const bf16x8*)&Bh[cb][gb];
                bf16x8 b0l = *(const bf16x8*)&Bl[cb][gb];
                bf16x8 b1h = *(const bf16x8*)&Bh[cb][gb + 128];
                bf16x8 b1l = *(const bf16x8*)&Bl[cb][gb + 128];
                acc00 = __builtin_amdgcn_mfma_f32_16x16x32_bf16(a0h, b0h, acc00, 0, 0, 0);
                acc00 = __builtin_amdgcn_mfma_f32_16x16x32_bf16(a0h, b0l, acc00, 0, 0, 0);
                acc00 = __builtin_amdgcn_mfma_f32_16x16x32_bf16(a0l, b0h, acc00, 0, 0, 0);
                acc01 = __builtin_amdgcn_mfma_f32_16x16x32_bf16(a0h, b1h, acc01, 0, 0, 0);
                acc01 = __builtin_amdgcn_mfma_f32_16x16x32_bf16(a0h, b1l, acc01, 0, 0, 0);
                acc01 = __builtin_amdgcn_mfma_f32_16x16x32_bf16(a0l, b1h, acc01, 0, 0, 0);
                acc10 = __builtin_amdgcn_mfma_f32_16x16x32_bf16(a1h, b0h, acc10, 0, 0, 0);
                acc10 = __builtin_amdgcn_mfma_f32_16x16x32_bf16(a1h, b0l, acc10, 0, 0, 0);
                acc10 = __builtin_amdgcn_mfma_f32_16x16x32_bf16(a1l, b0h, acc10, 0, 0, 0);
                acc11 = __builtin_amdgcn_mfma_f32_16x16x32_bf16(a1h, b1h, acc11, 0, 0, 0);
                acc11 = __builtin_amdgcn_mfma_f32_16x16x32_bf16(a1h, b1l, acc11, 0, 0, 0);
                acc11 = __builtin_amdgcn_mfma_f32_16x16x32_bf16(a1l, b1h, acc11, 0, 0, 0);
            }
        }
#undef STAGE
        int colb = nbase + nh;
        int col0 = colb + lrow;
        int col1 = col0 + 16;
        float bv0 = bias_ext[col0];
        float bv1 = bias_ext[col1];
        if (colb < C_D1) {
            int o0 = col0 - C_HT, o1 = col1 - C_HT;
#pragma unroll
            for (int r = 0; r < 4; ++r) {
                int row0 = rowb + r0 + r;
                int row1 = row0 + 16;
                HTb[(size_t)row0 * 512 + o0] = f2bf(acc00[r] + bv0);
                HTb[(size_t)row0 * 512 + o1] = f2bf(acc01[r] + bv1);
                HTb[(size_t)row1 * 512 + o0] = f2bf(acc10[r] + bv0);
                HTb[(size_t)row1 * 512 + o1] = f2bf(acc11[r] + bv1);
            }
        } else {
#pragma unroll
            for (int r = 0; r < 4; ++r) {
                int row0 = rowb + r0 + r;
                int row1 = row0 + 16;
                Pout[(size_t)row0 * NP + col0] = acc00[r] + bv0;
                Pout[(size_t)row0 * NP + col1] = acc01[r] + bv1;
                Pout[(size_t)row1 * NP + col0] = acc10[r] + bv0;
                Pout[(size_t)row1 * NP + col1] = acc11[r] + bv1;
            }
        }
    } else {
        // ---------- paired P1/P2 chunk: 1-term, reduce to c0 ----------
        int j = y;
        const ushort* aH  = A_hi + (size_t)(mbase + lane) * IND;
        const ushort* b1H = B_hi + (size_t)((j << 6) + lane) * IND;
        const ushort* b2H = B_hi + (size_t)(512 + (j << 6) + lane) * IND;
        f32x4 z4 = {0.f, 0.f, 0.f, 0.f};
        f32x4 p00 = z4, p01 = z4, p10 = z4, p11 = z4;
        f32x4 q00 = z4, q01 = z4, q10 = z4, q11 = z4;
#define STAGEP(BUF, C) { \
    int ck = (C) << 6; \
    if (wid == 0) { \
        _Pragma("unroll") \
        for (int g = 0; g < 8; g++) gl16(aH + ck + (g << 3), &Ah[BUF][g << 9]); \
    } else if (wid == 1) { \
        _Pragma("unroll") \
        for (int g = 0; g < 8; g++) gl16(b1H + ck + (g << 3), &Bh[BUF][g << 9]); \
    } else if (wid == 2) { \
        _Pragma("unroll") \
        for (int g = 0; g < 8; g++) gl16(b2H + ck + (g << 3), &Al[BUF][g << 9]); \
    } }
        STAGEP(0, 0)
        for (int c = 0; c < 8; c++) {
            int cb = c & 1;
            __syncthreads();
            if (c < 7) STAGEP(cb ^ 1, c + 1)
#pragma unroll
            for (int KS = 0; KS < 2; KS++) {
                int gA = (KS << 2) + (lane >> 4);
                int ga = ((gA << 6) + mh + lrow) << 3;
                int gb = ((gA << 6) + nh + lrow) << 3;
                bf16x8 a0h = *(const bf16x8*)&Ah[cb][ga];
                bf16x8 a1h = *(const bf16x8*)&Ah[cb][ga + 128];
                bf16x8 b10 = *(const bf16x8*)&Bh[cb][gb];
                bf16x8 b11 = *(const bf16x8*)&Bh[cb][gb + 128];
                bf16x8 b20 = *(const bf16x8*)&Al[cb][gb];
                bf16x8 b21 = *(const bf16x8*)&Al[cb][gb + 128];
                p00 = __builtin_amdgcn_mfma_f32_16x16x32_bf16(a0h, b10, p00, 0, 0, 0);
                p01 = __builtin_amdgcn_mfma_f32_16x16x32_bf16(a0h, b11, p01, 0, 0, 0);
                p10 = __builtin_amdgcn_mfma_f32_16x16x32_bf16(a1h, b10, p10, 0, 0, 0);
                p11 = __builtin_amdgcn_mfma_f32_16x16x32_bf16(a1h, b11, p11, 0, 0, 0);
                q00 = __builtin_amdgcn_mfma_f32_16x16x32_bf16(a0h, b20, q00, 0, 0, 0);
                q01 = __builtin_amdgcn_mfma_f32_16x16x32_bf16(a0h, b21, q01, 0, 0, 0);
                q10 = __builtin_amdgcn_mfma_f32_16x16x32_bf16(a1h, b20, q10, 0, 0, 0);
                q11 = __builtin_amdgcn_mfma_f32_16x16x32_bf16(a1h, b21, q11, 0, 0, 0);
            }
        }
#undef STAGEP
        int o0 = (j << 6) + nh + lrow;
        float b1v0 = bias_ext[C_P1 + o0], b1v1 = bias_ext[C_P1 + o0 + 16];
        float b2v0 = bias_ext[C_P2 + o0], b2v1 = bias_ext[C_P2 + o0 + 16];
#pragma unroll
        for (int r = 0; r < 4; ++r) {
            float sa = (p00[r] + b1v0) * (q00[r] + b2v0)
                     + (p01[r] + b1v1) * (q01[r] + b2v1);
            float sb = (p10[r] + b1v0) * (q10[r] + b2v0)
                     + (p11[r] + b1v1) * (q11[r] + b2v1);
            sa += __shfl_xor(sa, 1, 16); sa += __shfl_xor(sa, 2, 16);
            sa += __shfl_xor(sa, 4, 16); sa += __shfl_xor(sa, 8, 16);
            sb += __shfl_xor(sb, 1, 16); sb += __shfl_xor(sb, 2, 16);
            sb += __shfl_xor(sb, 4, 16); sb += __shfl_xor(sb, 8, 16);
            if (lrow == 0) {
                atomicAdd(&c0buf[rowb + r0 + r], sa);
                atomicAdd(&c0buf[rowb + 16 + r0 + r], sb);
            }
        }
    }
}

// ================= k5: 4 rows/block; c0 from buffer; softmax + shared-HT =================
__global__ __launch_bounds__(256) void k5_out(
    const float* __restrict__ P, const int* __restrict__ dep,
    const ushort* __restrict__ HTb, const float* __restrict__ bias,
    const float* __restrict__ c0buf, float* __restrict__ out) {
    int blk = blockIdx.x;
    int b = blk >> 5;
    int i0 = b * 128 + (blk & 31) * 4;
    int tid = threadIdx.x;
    int wr = tid >> 6, lane = tid & 63;
    __shared__ float a[4][NL];
    __shared__ float c0s[4];
    __shared__ float comb[4][48];
    __shared__ float invs[4];

    if (tid < 4) c0s[tid] = c0buf[i0 + tid];
    for (int idx = tid; idx < 4 * 45; idx += 256) {
        int r = idx / 45, t = idx - r * 45;
        const float* Prow = P + (size_t)(i0 + r) * NP;
        comb[r][t] = Prow[C_D1 + t] + Prow[C_D2 + t];
    }
    __syncthreads();

#pragma unroll
    for (int k = 0; k < 2; k++) {
        int idx = tid + k * 256;
        int r = idx >> 7, j = idx & 127;
        int tt = dep[(size_t)(i0 + r) * NL + j];
        a[r][j] = (tt != 0) ? expf(c0s[r] + comb[r][tt]) : 0.f;
    }
    __syncthreads();
    {
        float v = a[wr][lane] + a[wr][lane + 64];
        for (int off = 32; off; off >>= 1) v += __shfl_down(v, off, 64);
        if (lane == 0) invs[wr] = 1.0f / (v + 1e-6f);
    }
    __syncthreads();

    int o2 = tid * 2;
    float s00 = 0.f, s01 = 0.f, s10 = 0.f, s11 = 0.f;
    float s20 = 0.f, s21 = 0.f, s30 = 0.f, s31 = 0.f;
    const ushort* hp = HTb + (size_t)b * NL * 512 + o2;
#pragma unroll 8
    for (int j = 0; j < NL; j++) {
        ushort2 hv = *(const ushort2*)(hp + (size_t)j * 512);
        float h0 = bf2f(hv.x), h1 = bf2f(hv.y);
        float a0 = a[0][j], a1 = a[1][j], a2 = a[2][j], a3 = a[3][j];
        s00 += a0 * h0; s01 += a0 * h1;
        s10 += a1 * h0; s11 += a1 * h1;
        s20 += a2 * h0; s21 += a2 * h1;
        s30 += a3 * h0; s31 += a3 * h1;
    }
    float bv0 = bias[o2], bv1 = bias[o2 + 1];
    float i0v = invs[0], i1v = invs[1], i2v = invs[2], i3v = invs[3];
    float2 o;
    o.x = fmaxf(s00 * i0v + bv0, 0.f); o.y = fmaxf(s01 * i0v + bv1, 0.f);
    *(float2*)&out[(size_t)(i0 + 0) * 512 + o2] = o;
    o.x = fmaxf(s10 * i1v + bv0, 0.f); o.y = fmaxf(s11 * i1v + bv1, 0.f);
    *(float2*)&out[(size_t)(i0 + 1) * 512 + o2] = o;
    o.x = fmaxf(s20 * i2v + bv0, 0.f); o.y = fmaxf(s21 * i2v + bv1, 0.f);
    *(float2*)&out[(size_t)(i0 + 2) * 512 + o2] = o;
    o.x = fmaxf(s30 * i3v + bv0, 0.f); o.y = fmaxf(s31 * i3v + bv1, 0.f);
    *(float2*)&out[(size_t)(i0 + 3) * 512 + o2] = o;
}

extern "C" void kernel_launch(void* const* d_in, const int* in_sizes, int n_in,
                              void* d_out, int out_size, void* d_ws, size_t ws_size,
                              hipStream_t stream) {
    const float* h    = (const float*)d_in[0];
    const int* dep    = (const int*)d_in[1];
    const unsigned char* mask = (const unsigned char*)d_in[2];
    const float* emb  = (const float*)d_in[3];
    const float* W1   = (const float*)d_in[4];
    const float* b1   = (const float*)d_in[5];
    const float* W2   = (const float*)d_in[6];
    const float* b2   = (const float*)d_in[7];
    const float* Wg   = (const float*)d_in[8];
    const float* bg   = (const float*)d_in[9];
    const float* bias = (const float*)d_in[10];
    float* out = (float*)d_out;

    char* p = (char*)d_ws;
    ushort* A_hi = (ushort*)p;  p += (size_t)1024 * 512 * 2;   // 1 MB
    ushort* A_lo = (ushort*)p;  p += (size_t)1024 * 512 * 2;
    ushort* B_hi = (ushort*)p;  p += (size_t)NP * 512 * 2;     // 1.7 MB
    ushort* B_lo = (ushort*)p;  p += (size_t)NP * 512 * 2;
    ushort* HTb = (ushort*)p;   p += (size_t)1024 * 512 * 2;   // 1 MB
    float* bias_ext = (float*)p; p += NP * 4;
    float* c0buf = (float*)p;   p += 1024 * 4;
    float* Pout = (float*)p;    // 1024*1664*4 (only D region written)

    k_prep<<<324, 256, 0, stream>>>(h, mask, emb, W1, W2, Wg, b1, b2, bg,
                                    A_hi, A_lo, B_hi, B_lo, bias_ext, c0buf);
    dim3 g3(16, 18);
    k3_gemm<<<g3, 256, 0, stream>>>(A_hi, A_lo, B_hi, B_lo, bias_ext, Pout,
                                    HTb, c0buf);
    k5_out<<<256, 256, 0, stream>>>(Pout, dep, HTb, bias, c0buf, out);
}

// Round 18
// 48.560 us; speedup vs baseline: 1.0281x; 1.0281x over previous
//
#include <hip/hip_runtime.h>
#include <hip/hip_bf16.h>
#include <math.h>

#define NBATCH 8
#define NL 128
#define IND 512
#define DEPN 45
#define DEPD 16
#define WCOLS 528          // IN_DIM + DEP_DIM
#define NP 1664            // extended width (P1|P2|HT|D1|D2|pad)
#define C_P1 0
#define C_P2 512
#define C_HT 1024
#define C_D1 1536
#define C_D2 1581
#define C_PAD 1626

typedef __attribute__((ext_vector_type(8))) short bf16x8;
typedef __attribute__((ext_vector_type(4))) float f32x4;

__device__ inline ushort f2bf(float x) {
    __hip_bfloat16 b = __float2bfloat16(x);
    return *reinterpret_cast<ushort*>(&b);
}
__device__ inline float bf2f(ushort u) {
    __hip_bfloat16 b;
    *reinterpret_cast<ushort*>(&b) = u;
    return __bfloat162float(b);
}

__device__ __forceinline__ void gl16(const ushort* g, ushort* l) {
    __builtin_amdgcn_global_load_lds(
        (const __attribute__((address_space(1))) unsigned int*)g,
        (__attribute__((address_space(3))) unsigned int*)l, 16, 0, 0);
}

// ================= k_prep (R14 structure; B_lo skipped for rows<1024) =================
__global__ __launch_bounds__(256) void k_prep(
    const float* __restrict__ h, const unsigned char* __restrict__ mask,
    const float* __restrict__ emb,
    const float* __restrict__ W1, const float* __restrict__ W2,
    const float* __restrict__ Wg,
    const float* __restrict__ b1, const float* __restrict__ b2,
    const float* __restrict__ bg,
    ushort* __restrict__ A_hi, ushort* __restrict__ A_lo,
    ushort* __restrict__ B_hi, ushort* __restrict__ B_lo,
    float* __restrict__ bias_ext) {
    int bid = blockIdx.x;
    int tid = threadIdx.x;

    if (bid < 64) {
        int rb = bid * 16;
        int b = rb >> 7;
        __shared__ int sflag, smin, smax;
        __shared__ float w16[16];
        if (tid == 0) { sflag = 0; smin = NL; smax = -1; }
        __syncthreads();
        const int* mi = (const int*)mask;
        if (tid < 128) {
            int v0 = mi[tid], v1 = mi[tid + 128];
            if ((unsigned)v0 > 1u || (unsigned)v1 > 1u) atomicOr(&sflag, 1);
        }
        __syncthreads();
        if (tid < 128) {
            int mval = sflag ? (int)mask[b * NL + tid] : mi[b * NL + tid];
            if (mval) { atomicMin(&smin, tid); atomicMax(&smax, tid); }
        }
        __syncthreads();
        if (tid < 16) {
            int any = (smax >= 0);
            int s = any ? smin : 0;
            int e = any ? smax : (NL - 1);
            int i = (rb & 127) + tid;
            const float invL = 1.0f / (float)NL;
            float w;
            if (i < s)      w = 1.0f - (float)(s - i) * invL;
            else if (i > e) w = 1.0f - (float)(i - e) * invL;
            else            w = 0.0f;
            int mval = sflag ? (int)mask[b * NL + i] : mi[b * NL + i];
            if (mval) w = 0.0f;
            w16[tid] = w;
        }
        __syncthreads();
        for (int idx = tid; idx < 16 * 128; idx += 256) {
            int r = idx >> 7, dc = (idx & 127) << 2;
            float4 hv = *(const float4*)&h[(size_t)(rb + r) * IND + dc];
            float wv = w16[r];
            hv.x *= wv; hv.y *= wv; hv.z *= wv; hv.w *= wv;
            ushort4 hi4, lo4;
            hi4.x = f2bf(hv.x); hi4.y = f2bf(hv.y); hi4.z = f2bf(hv.z); hi4.w = f2bf(hv.w);
            lo4.x = f2bf(hv.x - bf2f(hi4.x));
            lo4.y = f2bf(hv.y - bf2f(hi4.y));
            lo4.z = f2bf(hv.z - bf2f(hi4.z));
            lo4.w = f2bf(hv.w - bf2f(hi4.w));
            *(ushort4*)&A_hi[(size_t)(rb + r) * IND + dc] = hi4;
            *(ushort4*)&A_lo[(size_t)(rb + r) * IND + dc] = lo4;
        }
        if (bid == 0) {
            for (int i = tid; i < 512; i += 256) {
                bias_ext[C_P1 + i] = b1[i];
                bias_ext[C_P2 + i] = b2[i];
                bias_ext[C_HT + i] = bg[i];
            }
            if (tid < NP - C_PAD) bias_ext[C_PAD + tid] = 0.f;
        }
    } else if (bid < 160) {
        int nb = (bid - 64) * 16;
        for (int idx = tid; idx < 16 * 128; idx += 256) {
            int r = idx >> 7, dc = (idx & 127) << 2;
            int n = nb + r;
            const float* src;
            if (n < 512)       src = W1 + (size_t)n * WCOLS + dc;
            else if (n < 1024) src = W2 + (size_t)(n - 512) * WCOLS + dc;
            else               src = Wg + (size_t)(n - 1024) * IND + dc;
            float4 wv = *(const float4*)src;
            ushort4 hi4;
            hi4.x = f2bf(wv.x); hi4.y = f2bf(wv.y); hi4.z = f2bf(wv.z); hi4.w = f2bf(wv.w);
            *(ushort4*)&B_hi[(size_t)n * IND + dc] = hi4;
            if (n >= 1024) {   // lo only needed for HT/D chunks (3-term region)
                ushort4 lo4;
                lo4.x = f2bf(wv.x - bf2f(hi4.x));
                lo4.y = f2bf(wv.y - bf2f(hi4.y));
                lo4.z = f2bf(wv.z - bf2f(hi4.z));
                lo4.w = f2bf(wv.w - bf2f(hi4.w));
                *(ushort4*)&B_lo[(size_t)n * IND + dc] = lo4;
            }
        }
    } else if (bid < 162) {
        int nb = 1626 + (bid - 160) * 19;
        ushort4 z4 = {0, 0, 0, 0};
        for (int idx = tid; idx < 19 * 128; idx += 256) {
            int r = idx >> 7, dc = (idx & 127) << 2;
            *(ushort4*)&B_hi[(size_t)(nb + r) * IND + dc] = z4;
            *(ushort4*)&B_lo[(size_t)(nb + r) * IND + dc] = z4;
        }
    } else if (bid < 234) {
        int zi = bid - 162;               // 0..71
        int m = zi / 36;
        int rest = zi % 36;
        int dq = rest / 9;
        int tq = rest % 9;
        int tb = tq * 5;
        __shared__ float es5[5][DEPD];
        __shared__ float ys5[5][512];
        __shared__ float part[5][256];
        if (tid < 5 * DEPD) es5[tid >> 4][tid & 15] = emb[(tb + (tid >> 4)) * DEPD + (tid & 15)];
        __syncthreads();
        const float* Wdep = (m == 0) ? W2 : W1;
        for (int idx = tid; idx < 5 * 512; idx += 256) {
            int tt = idx >> 9, o = idx & 511;
            float s = 0.f;
#pragma unroll
            for (int e = 0; e < DEPD; e++) s += es5[tt][e] * Wdep[o * WCOLS + IND + e];
            ys5[tt][o] = s;
        }
        __syncthreads();
        int dloc = tid & 127, half = tid >> 7;
        const float* Wsrc = (m == 0) ? W1 : W2;
        int d = dq * 128 + dloc;
        int obase = half * 256;
        float ac0 = 0.f, ac1 = 0.f, ac2 = 0.f, ac3 = 0.f, ac4 = 0.f;
#pragma unroll 8
        for (int oo = 0; oo < 256; oo++) {
            float w = Wsrc[(size_t)(obase + oo) * WCOLS + d];
            int o = obase + oo;
            ac0 += w * ys5[0][o];
            ac1 += w * ys5[1][o];
            ac2 += w * ys5[2][o];
            ac3 += w * ys5[3][o];
            ac4 += w * ys5[4][o];
        }
        part[0][tid] = ac0; part[1][tid] = ac1; part[2][tid] = ac2;
        part[3][tid] = ac3; part[4][tid] = ac4;
        __syncthreads();
        if (half == 0) {
#pragma unroll
            for (int tt = 0; tt < 5; tt++) {
                float tot = part[tt][dloc] + part[tt][128 + dloc];
                int row = ((m == 0) ? C_D1 : C_D2) + tb + tt;
                ushort hi = f2bf(tot);
                B_hi[(size_t)row * IND + d] = hi;
                B_lo[(size_t)row * IND + d] = f2bf(tot - bf2f(hi));
            }
        }
    } else {
        int zi2 = bid - 234;              // 0..89
        int t = zi2 % 45;
        int m = zi2 / 45;
        __shared__ float es[DEPD];
        __shared__ float ys[512];
        __shared__ float y1s[512];
        if (tid < DEPD) es[tid] = emb[t * DEPD + tid];
        __syncthreads();
        const float* Wdep = (m == 0) ? W2 : W1;
        for (int o = tid; o < 512; o += 256) {
            float s = 0.f;
#pragma unroll
            for (int e = 0; e < DEPD; e++) s += es[e] * Wdep[o * WCOLS + IND + e];
            ys[o] = s;
        }
        if (m == 0) {
            for (int o = tid; o < 512; o += 256) {
                float s = 0.f;
#pragma unroll
                for (int e = 0; e < DEPD; e++) s += es[e] * W1[o * WCOLS + IND + e];
                y1s[o] = s;
            }
        }
        __syncthreads();
        if (tid < 64) {
            const float* bb = (m == 0) ? b1 : b2;
            float sb = 0.f;
#pragma unroll
            for (int k = 0; k < 8; k++) sb += bb[tid + k * 64] * ys[tid + k * 64];
            if (m == 0) {
#pragma unroll
                for (int k = 0; k < 8; k++) sb += y1s[tid + k * 64] * ys[tid + k * 64];
            }
            for (int off = 32; off; off >>= 1) sb += __shfl_down(sb, off, 64);
            if (tid == 0) bias_ext[((m == 0) ? C_D1 : C_D2) + t] = sb;
        }
    }
}

// ================= k3: precision-tiered, double-buffered MFMA GEMM =================
// Grid (16, 26), 256 thr = 4 waves (2m x 2n wave grid, 32x32 each), 64x64 tile.
// n-chunks < C_HT (P1/P2): 1-term Ah.Bh (c0 is per-row constant -> cancels in
// softmax normalization; bf16 precision suffices). n-chunks >= C_HT (HT|D):
// full 3-term hi/lo. Double-buffered LDS, global_load_lds staging.
__global__ __launch_bounds__(256) void k3_gemm(
    const ushort* __restrict__ A_hi, const ushort* __restrict__ A_lo,
    const ushort* __restrict__ B_hi, const ushort* __restrict__ B_lo,
    const float* __restrict__ bias_ext, float* __restrict__ Pout,
    ushort* __restrict__ HTb) {
    int tid = threadIdx.x;
    int wid = tid >> 6, lane = tid & 63;
    int lrow = lane & 15;
    int mbase = blockIdx.x * 64;
    int nbase = blockIdx.y * 64;
    int mh = (wid >> 1) << 5;
    int nh = (wid & 1) << 5;

    __shared__ ushort Ah[2][8 * 64 * 8];
    __shared__ ushort Al[2][8 * 64 * 8];
    __shared__ ushort Bh[2][8 * 64 * 8];
    __shared__ ushort Bl[2][8 * 64 * 8];

    const ushort* aH = A_hi + (size_t)(mbase + lane) * IND;
    const ushort* aL = A_lo + (size_t)(mbase + lane) * IND;
    const ushort* bH = B_hi + (size_t)(nbase + lane) * IND;
    const ushort* bL = B_lo + (size_t)(nbase + lane) * IND;

    f32x4 acc00 = {0.f, 0.f, 0.f, 0.f};
    f32x4 acc01 = acc00, acc10 = acc00, acc11 = acc00;

    if (nbase >= C_HT) {
        // ---------- full 3-term path (HT | D1 | D2 | pad) ----------
#define STAGE(BUF, C) { \
    int ck = (C) << 6; \
    if (wid == 0) { \
        _Pragma("unroll") \
        for (int g = 0; g < 8; g++) gl16(aH + ck + (g << 3), &Ah[BUF][g << 9]); \
    } else if (wid == 1) { \
        _Pragma("unroll") \
        for (int g = 0; g < 8; g++) gl16(aL + ck + (g << 3), &Al[BUF][g << 9]); \
    } else if (wid == 2) { \
        _Pragma("unroll") \
        for (int g = 0; g < 8; g++) gl16(bH + ck + (g << 3), &Bh[BUF][g << 9]); \
    } else { \
        _Pragma("unroll") \
        for (int g = 0; g < 8; g++) gl16(bL + ck + (g << 3), &Bl[BUF][g << 9]); \
    } }
        STAGE(0, 0)
        for (int c = 0; c < 8; c++) {
            int cb = c & 1;
            __syncthreads();
            if (c < 7) STAGE(cb ^ 1, c + 1)
#pragma unroll
            for (int KS = 0; KS < 2; KS++) {
                int gA = (KS << 2) + (lane >> 4);
                int ga = ((gA << 6) + mh + lrow) << 3;
                int gb = ((gA << 6) + nh + lrow) << 3;
                bf16x8 a0h = *(const bf16x8*)&Ah[cb][ga];
                bf16x8 a0l = *(const bf16x8*)&Al[cb][ga];
                bf16x8 a1h = *(const bf16x8*)&Ah[cb][ga + 128];
                bf16x8 a1l = *(const bf16x8*)&Al[cb][ga + 128];
                bf16x8 b0h = *(const bf16x8*)&Bh[cb][gb];
                bf16x8 b0l = *(const bf16x8*)&Bl[cb][gb];
                bf16x8 b1h = *(const bf16x8*)&Bh[cb][gb + 128];
                bf16x8 b1l = *(const bf16x8*)&Bl[cb][gb + 128];
                acc00 = __builtin_amdgcn_mfma_f32_16x16x32_bf16(a0h, b0h, acc00, 0, 0, 0);
                acc00 = __builtin_amdgcn_mfma_f32_16x16x32_bf16(a0h, b0l, acc00, 0, 0, 0);
                acc00 = __builtin_amdgcn_mfma_f32_16x16x32_bf16(a0l, b0h, acc00, 0, 0, 0);
                acc01 = __builtin_amdgcn_mfma_f32_16x16x32_bf16(a0h, b1h, acc01, 0, 0, 0);
                acc01 = __builtin_amdgcn_mfma_f32_16x16x32_bf16(a0h, b1l, acc01, 0, 0, 0);
                acc01 = __builtin_amdgcn_mfma_f32_16x16x32_bf16(a0l, b1h, acc01, 0, 0, 0);
                acc10 = __builtin_amdgcn_mfma_f32_16x16x32_bf16(a1h, b0h, acc10, 0, 0, 0);
                acc10 = __builtin_amdgcn_mfma_f32_16x16x32_bf16(a1h, b0l, acc10, 0, 0, 0);
                acc10 = __builtin_amdgcn_mfma_f32_16x16x32_bf16(a1l, b0h, acc10, 0, 0, 0);
                acc11 = __builtin_amdgcn_mfma_f32_16x16x32_bf16(a1h, b1h, acc11, 0, 0, 0);
                acc11 = __builtin_amdgcn_mfma_f32_16x16x32_bf16(a1h, b1l, acc11, 0, 0, 0);
                acc11 = __builtin_amdgcn_mfma_f32_16x16x32_bf16(a1l, b1h, acc11, 0, 0, 0);
            }
        }
#undef STAGE
    } else {
        // ---------- light 1-term path (P1 | P2): Ah.Bh only ----------
#define STAGEL(BUF, C) { \
    int ck = (C) << 6; \
    if (wid == 0) { \
        _Pragma("unroll") \
        for (int g = 0; g < 4; g++) gl16(aH + ck + (g << 3), &Ah[BUF][g << 9]); \
    } else if (wid == 1) { \
        _Pragma("unroll") \
        for (int g = 4; g < 8; g++) gl16(aH + ck + (g << 3), &Ah[BUF][g << 9]); \
    } else if (wid == 2) { \
        _Pragma("unroll") \
        for (int g = 0; g < 4; g++) gl16(bH + ck + (g << 3), &Bh[BUF][g << 9]); \
    } else { \
        _Pragma("unroll") \
        for (int g = 4; g < 8; g++) gl16(bH + ck + (g << 3), &Bh[BUF][g << 9]); \
    } }
        STAGEL(0, 0)
        for (int c = 0; c < 8; c++) {
            int cb = c & 1;
            __syncthreads();
            if (c < 7) STAGEL(cb ^ 1, c + 1)
#pragma unroll
            for (int KS = 0; KS < 2; KS++) {
                int gA = (KS << 2) + (lane >> 4);
                int ga = ((gA << 6) + mh + lrow) << 3;
                int gb = ((gA << 6) + nh + lrow) << 3;
                bf16x8 a0h = *(const bf16x8*)&Ah[cb][ga];
                bf16x8 a1h = *(const bf16x8*)&Ah[cb][ga + 128];
                bf16x8 b0h = *(const bf16x8*)&Bh[cb][gb];
                bf16x8 b1h = *(const bf16x8*)&Bh[cb][gb + 128];
                acc00 = __builtin_amdgcn_mfma_f32_16x16x32_bf16(a0h, b0h, acc00, 0, 0, 0);
                acc01 = __builtin_amdgcn_mfma_f32_16x16x32_bf16(a0h, b1h, acc01, 0, 0, 0);
                acc10 = __builtin_amdgcn_mfma_f32_16x16x32_bf16(a1h, b0h, acc10, 0, 0, 0);
                acc11 = __builtin_amdgcn_mfma_f32_16x16x32_bf16(a1h, b1h, acc11, 0, 0, 0);
            }
        }
#undef STAGEL
    }

    int r0 = (lane >> 4) << 2;
    int colb = nbase + nh;
    int col0 = colb + lrow;
    int col1 = col0 + 16;
    float bv0 = bias_ext[col0];
    float bv1 = bias_ext[col1];
    int rowb = mbase + mh;

    if (colb >= C_HT && colb < C_HT + 512) {
        int o0 = col0 - C_HT, o1 = col1 - C_HT;
#pragma unroll
        for (int r = 0; r < 4; ++r) {
            int row0 = rowb + r0 + r;
            int row1 = row0 + 16;
            HTb[(size_t)row0 * 512 + o0] = f2bf(acc00[r] + bv0);
            HTb[(size_t)row0 * 512 + o1] = f2bf(acc01[r] + bv1);
            HTb[(size_t)row1 * 512 + o0] = f2bf(acc10[r] + bv0);
            HTb[(size_t)row1 * 512 + o1] = f2bf(acc11[r] + bv1);
        }
    } else {
#pragma unroll
        for (int r = 0; r < 4; ++r) {
            int row0 = rowb + r0 + r;
            int row1 = row0 + 16;
            Pout[(size_t)row0 * NP + col0] = acc00[r] + bv0;
            Pout[(size_t)row0 * NP + col1] = acc01[r] + bv1;
            Pout[(size_t)row1 * NP + col0] = acc10[r] + bv0;
            Pout[(size_t)row1 * NP + col1] = acc11[r] + bv1;
        }
    }
}

// ================= k5: 4 rows/block; softmax + shared-HT matmul (R14) =================
__global__ __launch_bounds__(256) void k5_out(
    const float* __restrict__ P, const int* __restrict__ dep,
    const ushort* __restrict__ HTb, const float* __restrict__ bias,
    float* __restrict__ out) {
    int blk = blockIdx.x;
    int b = blk >> 5;
    int i0 = b * 128 + (blk & 31) * 4;
    int tid = threadIdx.x;
    int wr = tid >> 6, lane = tid & 63;
    __shared__ float a[4][NL];
    __shared__ float c0s[4];
    __shared__ float comb[4][48];
    __shared__ float invs[4];

    {
        const float* p1 = P + (size_t)(i0 + wr) * NP + C_P1 + lane * 8;
        const float* p2 = P + (size_t)(i0 + wr) * NP + C_P2 + lane * 8;
        float4 x0 = *(const float4*)(p1);
        float4 x1 = *(const float4*)(p1 + 4);
        float4 y0 = *(const float4*)(p2);
        float4 y1 = *(const float4*)(p2 + 4);
        float s = x0.x * y0.x + x0.y * y0.y + x0.z * y0.z + x0.w * y0.w
                + x1.x * y1.x + x1.y * y1.y + x1.z * y1.z + x1.w * y1.w;
        for (int off = 32; off; off >>= 1) s += __shfl_down(s, off, 64);
        if (lane == 0) c0s[wr] = s;
    }
    for (int idx = tid; idx < 4 * 45; idx += 256) {
        int r = idx / 45, t = idx - r * 45;
        const float* Prow = P + (size_t)(i0 + r) * NP;
        comb[r][t] = Prow[C_D1 + t] + Prow[C_D2 + t];
    }
    __syncthreads();

#pragma unroll
    for (int k = 0; k < 2; k++) {
        int idx = tid + k * 256;
        int r = idx >> 7, j = idx & 127;
        int tt = dep[(size_t)(i0 + r) * NL + j];
        a[r][j] = (tt != 0) ? expf(c0s[r] + comb[r][tt]) : 0.f;
    }
    __syncthreads();
    {
        float v = a[wr][lane] + a[wr][lane + 64];
        for (int off = 32; off; off >>= 1) v += __shfl_down(v, off, 64);
        if (lane == 0) invs[wr] = 1.0f / (v + 1e-6f);
    }
    __syncthreads();

    int o2 = tid * 2;
    float s00 = 0.f, s01 = 0.f, s10 = 0.f, s11 = 0.f;
    float s20 = 0.f, s21 = 0.f, s30 = 0.f, s31 = 0.f;
    const ushort* hp = HTb + (size_t)b * NL * 512 + o2;
#pragma unroll 8
    for (int j = 0; j < NL; j++) {
        ushort2 hv = *(const ushort2*)(hp + (size_t)j * 512);
        float h0 = bf2f(hv.x), h1 = bf2f(hv.y);
        float a0 = a[0][j], a1 = a[1][j], a2 = a[2][j], a3 = a[3][j];
        s00 += a0 * h0; s01 += a0 * h1;
        s10 += a1 * h0; s11 += a1 * h1;
        s20 += a2 * h0; s21 += a2 * h1;
        s30 += a3 * h0; s31 += a3 * h1;
    }
    float bv0 = bias[o2], bv1 = bias[o2 + 1];
    float i0v = invs[0], i1v = invs[1], i2v = invs[2], i3v = invs[3];
    float2 o;
    o.x = fmaxf(s00 * i0v + bv0, 0.f); o.y = fmaxf(s01 * i0v + bv1, 0.f);
    *(float2*)&out[(size_t)(i0 + 0) * 512 + o2] = o;
    o.x = fmaxf(s10 * i1v + bv0, 0.f); o.y = fmaxf(s11 * i1v + bv1, 0.f);
    *(float2*)&out[(size_t)(i0 + 1) * 512 + o2] = o;
    o.x = fmaxf(s20 * i2v + bv0, 0.f); o.y = fmaxf(s21 * i2v + bv1, 0.f);
    *(float2*)&out[(size_t)(i0 + 2) * 512 + o2] = o;
    o.x = fmaxf(s30 * i3v + bv0, 0.f); o.y = fmaxf(s31 * i3v + bv1, 0.f);
    *(float2*)&out[(size_t)(i0 + 3) * 512 + o2] = o;
}

extern "C" void kernel_launch(void* const* d_in, const int* in_sizes, int n_in,
                              void* d_out, int out_size, void* d_ws, size_t ws_size,
                              hipStream_t stream) {
    const float* h    = (const float*)d_in[0];
    const int* dep    = (const int*)d_in[1];
    const unsigned char* mask = (const unsigned char*)d_in[2];
    const float* emb  = (const float*)d_in[3];
    const float* W1   = (const float*)d_in[4];
    const float* b1   = (const float*)d_in[5];
    const float* W2   = (const float*)d_in[6];
    const float* b2   = (const float*)d_in[7];
    const float* Wg   = (const float*)d_in[8];
    const float* bg   = (const float*)d_in[9];
    const float* bias = (const float*)d_in[10];
    float* out = (float*)d_out;

    char* p = (char*)d_ws;
    ushort* A_hi = (ushort*)p;  p += (size_t)1024 * 512 * 2;   // 1 MB
    ushort* A_lo = (ushort*)p;  p += (size_t)1024 * 512 * 2;
    ushort* B_hi = (ushort*)p;  p += (size_t)NP * 512 * 2;     // 1.7 MB
    ushort* B_lo = (ushort*)p;  p += (size_t)NP * 512 * 2;
    ushort* HTb = (ushort*)p;   p += (size_t)1024 * 512 * 2;   // 1 MB
    float* bias_ext = (float*)p; p += NP * 4;
    float* Pout = (float*)p;    // 1024*1664*4 (HT region unused)

    k_prep<<<324, 256, 0, stream>>>(h, mask, emb, W1, W2, Wg, b1, b2, bg,
                                    A_hi, A_lo, B_hi, B_lo, bias_ext);
    dim3 g3(16, 26);
    k3_gemm<<<g3, 256, 0, stream>>>(A_hi, A_lo, B_hi, B_lo, bias_ext, Pout, HTb);
    k5_out<<<256, 256, 0, stream>>>(Pout, dep, HTb, bias, out);
}